// Round 9
// baseline (126.966 us; speedup 1.0000x reference)
//
#include <hip/hip_runtime.h>
#include <hip/hip_bf16.h>

// out[b,d,r] = sum_c p[b,c] * softmax_d( x[b,:] @ W[:, c*8+d, r] + bias[c,d,r] )
// B=16384, F=128, C=8, R=64.  bf16 MFMA 16x16x32, fully fused.
//
// R8->R9: R8 was latency-bound at 8 waves/CU (occ 17%, no pipe >37%).
// The 8 i-values per wave are DISJOINT output columns -> split i across
// waves with zero reduction cost.  Block: 512 thr = 8 waves = 4 m-tile
// pairs x 2 i-halves; same 128 rows, same 64 KB double-buffered stage,
// grid 512 -> 2 blocks/CU = 16 waves/CU.  Per-wave regs ~110 -> fits the
// launch_bounds(512,4) 128-reg (arch+acc) budget without spilling.

#define B_ROWS   16384
#define F_DIM    128
#define NCOL     4096      // C*C*R
#define OUT_STRIDE 512     // C*R
#define LOG2E    1.44269504088896340736f

typedef __bf16 bf16x8 __attribute__((ext_vector_type(8)));
typedef float  f32x4  __attribute__((ext_vector_type(4)));

#define AS1(p) ((const __attribute__((address_space(1))) unsigned int*)(p))
#define AS3(p) ((__attribute__((address_space(3))) unsigned int*)(p))

// DPP-assisted partial-group add: s + permute(s).  CTRL: 0xB1 = quad_perm
// [1,0,3,2] (xor1), 0x4E = quad_perm [2,3,0,1] (xor2), 0x128 = row_ror:8.
template <int CTRL>
__device__ __forceinline__ float dpp_add(float s) {
    int si = __builtin_bit_cast(int, s);
    int pi = __builtin_amdgcn_update_dpp(0, si, CTRL, 0xf, 0xf, true);
    return s + __builtin_bit_cast(float, pi);
}

// xor-4 lane swizzle (exchanges the rb pair).  BitMode offset 0x101F.
__device__ __forceinline__ float swz4(float v) {
    return __builtin_bit_cast(float,
        __builtin_amdgcn_ds_swizzle(__builtin_bit_cast(int, v), 0x101F));
}

// Column mapping: tile T in [0,256) = c*32 + w*8 + i; col4 in [0,16):
//   d = (col4&3) | ((col4>>1)&4) ; r = w*16 + i*2 + ((col4>>2)&1)
// Original W column n_orig = (c*8+d)*64 + r.

// ---------------------------------------------------------------------------
// Prepass 1: W fp32 (128 x 4096) -> bf16 MFMA B-fragments (permuted cols).
// ---------------------------------------------------------------------------
__global__ void wconv_kernel(const float* __restrict__ W, __bf16* __restrict__ wf) {
    int f    = blockIdx.x * 256 + threadIdx.x;  // 0..65535
    int lane = f & 63;
    int tkk  = f >> 6;
    int T    = tkk >> 2;
    int kk   = tkk & 3;
    int c    = T >> 5;
    int w    = (T >> 3) & 3;
    int i    = T & 7;
    int col4 = lane & 15;
    int d    = (col4 & 3) | ((col4 >> 1) & 4);
    int r    = w * 16 + i * 2 + ((col4 >> 2) & 1);
    int n    = (c * 8 + d) * 64 + r;
    int kbase = kk * 32 + (lane >> 4) * 8;
    bf16x8 frag;
    for (int j = 0; j < 8; ++j)
        frag[j] = (__bf16)W[(kbase + j) * NCOL + n];
    *(bf16x8*)(wf + f * 8) = frag;
}

// ---------------------------------------------------------------------------
// Prepass 2: bias -> fragment-lane order, pre-scaled by log2(e).
// ---------------------------------------------------------------------------
__global__ void bconv_kernel(const float* __restrict__ bias, float* __restrict__ bs) {
    int t    = blockIdx.x * 256 + threadIdx.x;  // 0..16383
    int lane = t & 63;
    int T    = t >> 6;
    int c    = T >> 5;
    int w    = (T >> 3) & 3;
    int i    = T & 7;
    int col4 = lane & 15;
    int d    = (col4 & 3) | ((col4 >> 1) & 4);
    int r    = w * 16 + i * 2 + ((col4 >> 2) & 1);
    bs[t] = bias[(c * 8 + d) * 64 + r] * LOG2E;
}

// ---------------------------------------------------------------------------
// Fused GEMM + bias + softmax(d) + p-contraction + in-register transpose.
// Block: 512 thr (8 waves), 128 rows, one r-chunk w = blockIdx&3.
// Wave ww: m-tile pair mtp = ww&3 (rows b0+mtp*32..+32), i-half h = ww>>2
// (i = 4h..4h+3, i.e. output columns 8h..8h+8 of the w-span).
// ---------------------------------------------------------------------------
__global__ __launch_bounds__(512, 4)
void fused_kernel(const float* __restrict__ x, const float* __restrict__ p,
                  const float* __restrict__ bs, const __bf16* __restrict__ wf,
                  float* __restrict__ out) {
    __shared__ __align__(16) char lds[2][32768];   // double-buffered fragments

    const int lane = threadIdx.x & 63;
    const int ww   = threadIdx.x >> 6;   // wave 0..7
    const int mtp  = ww & 3;             // m-tile pair
    const int h    = ww >> 2;            // i-half
    const int quad = lane >> 4;
    const int l15  = lane & 15;
    const int w    = blockIdx.x & 3;     // r-chunk
    const int b0   = (blockIdx.x >> 2) * 128 + mtp * 32;
    const int d    = (l15 & 3) | ((l15 >> 1) & 4);
    const int rb   = (l15 >> 2) & 1;

    // A fragments: afr[mt][kk][j] = x_bf16[b0+mt*16+l15][kk*32 + quad*8 + j]
    bf16x8 afr[2][4];
#pragma unroll
    for (int mt = 0; mt < 2; ++mt) {
        const float* xr = x + (b0 + mt * 16 + l15) * F_DIM + quad * 8;
#pragma unroll
        for (int kk = 0; kk < 4; ++kk) {
            float4 lo = *(const float4*)(xr + kk * 32);
            float4 hi = *(const float4*)(xr + kk * 32 + 4);
            bf16x8 f;
            f[0] = (__bf16)lo.x; f[1] = (__bf16)lo.y;
            f[2] = (__bf16)lo.z; f[3] = (__bf16)lo.w;
            f[4] = (__bf16)hi.x; f[5] = (__bf16)hi.y;
            f[6] = (__bf16)hi.z; f[7] = (__bf16)hi.w;
            afr[mt][kk] = f;
        }
    }

    // stage c's 32 fragments (32 KB): wave ww takes fragments ww*4..ww*4+3
    auto stage = [&](int c, char* dst) {
        const __bf16* gbase = wf + (size_t)(c * 128 + w * 32) * 512 + lane * 8;
#pragma unroll
        for (int j = 0; j < 4; ++j) {
            int f = ww * 4 + j;
            __builtin_amdgcn_global_load_lds(AS1(gbase + f * 512),
                                             AS3(dst + f * 1024), 16, 0, 0);
        }
    };

    float O_all[2][4][4] = {};   // [mt][ii][jj], static-indexed

    stage(0, lds[0]);

#pragma unroll 1
    for (int c = 0; c < 8; ++c) {
        __syncthreads();                       // stage(c) done; buf[c&1] ready
        if (c < 7) stage(c + 1, lds[(c + 1) & 1]);
        const char* buf = lds[c & 1];

        float pvv[2][4];
#pragma unroll
        for (int mt = 0; mt < 2; ++mt)
#pragma unroll
            for (int jj = 0; jj < 4; ++jj)
                pvv[mt][jj] = p[(b0 + mt * 16 + quad * 4 + jj) * 8 + c];

#pragma unroll
        for (int ii = 0; ii < 4; ++ii) {
            const int i = h * 4 + ii;
            f32x4 acc0 = {0.f, 0.f, 0.f, 0.f};
            f32x4 acc1 = {0.f, 0.f, 0.f, 0.f};
#pragma unroll
            for (int kk = 0; kk < 4; ++kk) {
                bf16x8 bfr = *(const bf16x8*)(buf + (i * 4 + kk) * 1024 + lane * 16);
                acc0 = __builtin_amdgcn_mfma_f32_16x16x32_bf16(afr[0][kk], bfr, acc0, 0, 0, 0);
                acc1 = __builtin_amdgcn_mfma_f32_16x16x32_bf16(afr[1][kk], bfr, acc1, 0, 0, 0);
            }
            float bvl = bs[(c * 32 + w * 8 + i) * 64 + lane];
#pragma unroll
            for (int mt = 0; mt < 2; ++mt) {
                const f32x4& acc = mt ? acc1 : acc0;
#pragma unroll
                for (int jj = 0; jj < 4; ++jj) {
                    float e = __builtin_amdgcn_exp2f(
                                  __builtin_fmaf(acc[jj], LOG2E, bvl));
                    float s = dpp_add<0xB1>(e);    // + xor1 (d bit 0)
                    s = dpp_add<0x4E>(s);          // + xor2 (d bit 1)
                    s = dpp_add<0x128>(s);         // + xor8 (d bit 2)
                    O_all[mt][ii][jj] = __builtin_fmaf(
                        e, pvv[mt][jj] * __builtin_amdgcn_rcpf(s), O_all[mt][ii][jj]);
                }
            }
        }
    }

    // ---- transpose (rb pair exchange) + coalesced stores -------------------
    // Wave covers column sub-offsets 8h + 2ii + rb.  Target: lane rb stores
    // 4 floats at cols 8h + rb*4 + m; src_ii = (rb*4+m)>>1, own iff (m&1)==rb.
    const bool bhi = (rb != 0);
#pragma unroll
    for (int mt = 0; mt < 2; ++mt) {
#pragma unroll
        for (int jj = 0; jj < 4; ++jj) {
            float S[4];
#pragma unroll
            for (int ii = 0; ii < 4; ++ii)
                S[ii] = swz4(O_all[mt][ii][jj]);
            float T[4];
#pragma unroll
            for (int m = 0; m < 4; ++m) {
                int ilo = m >> 1;            // for rb=0: cols 0..3
                int ihi = 2 + (m >> 1);      // for rb=1: cols 4..7
                float tlo = (m & 1) ? S[ilo]             : O_all[mt][ilo][jj];
                float thi = (m & 1) ? O_all[mt][ihi][jj] : S[ihi];
                T[m] = bhi ? thi : tlo;
            }
            float* orow = out + (b0 + mt * 16 + quad * 4 + jj) * OUT_STRIDE
                              + d * 64 + w * 16 + h * 8 + rb * 4;
            f32x4 v = {T[0], T[1], T[2], T[3]};
            *(f32x4*)(orow) = v;
        }
    }
}

extern "C" void kernel_launch(void* const* d_in, const int* in_sizes, int n_in,
                              void* d_out, int out_size, void* d_ws, size_t ws_size,
                              hipStream_t stream) {
    const float* x    = (const float*)d_in[0];   // (16384, 128)
    const float* p    = (const float*)d_in[1];   // (16384, 8)
    const float* W    = (const float*)d_in[2];   // (128, 64, 64)
    const float* bias = (const float*)d_in[3];   // (8, 8, 64)
    float* out = (float*)d_out;                  // (16384, 8, 64)
    __bf16* wf = (__bf16*)d_ws;                          // 1 MB fragments
    float*  bs = (float*)((char*)d_ws + (1 << 20));      // 64 KB swizzled bias

    wconv_kernel<<<dim3(256), dim3(256), 0, stream>>>(W, wf);
    bconv_kernel<<<dim3(64), dim3(256), 0, stream>>>(bias, bs);
    fused_kernel<<<dim3(512), dim3(512), 0, stream>>>(x, p, bs, wf, out);
}

// Round 10
// 105.728 us; speedup vs baseline: 1.2009x; 1.2009x over previous
//
#include <hip/hip_runtime.h>
#include <hip/hip_bf16.h>

// out[b,d,r] = sum_c p[b,c] * softmax_d( x[b,:] @ W[:, c*8+d, r] + bias[c,d,r] )
// B=16384, F=128, C=8, R=64.  bf16 MFMA 16x16x32, fully fused.
//
// R9->R10: DPP-layout epilogue costs ~7 VALU/elem (exp2+3dpp+rcp+mul+fma);
// the R1 layout (8 d-accumulators per lane) costs ~3.1 (one rcp + 7 adds
// per 8 elems) and stores are naturally coalesced (no transpose).  Its old
// register problem is solved by the R7 shell: 256 thr / 4 waves / 64 rows /
// grid 1024 / single-buffered 32 KB LDS stage (4 blocks/CU).  acc 32 +
// O 32 + afr 16 ~ 110 regs < 128 (launch_bounds(256,4)).  d-permute,
// transpose, and bconv deleted.

#define B_ROWS   16384
#define F_DIM    128
#define NCOL     4096      // C*C*R
#define OUT_STRIDE 512     // C*R
#define LOG2E    1.44269504088896340736f

typedef __bf16 bf16x8 __attribute__((ext_vector_type(8)));
typedef float  f32x4  __attribute__((ext_vector_type(4)));

#define AS1(p) ((const __attribute__((address_space(1))) unsigned int*)(p))
#define AS3(p) ((__attribute__((address_space(3))) unsigned int*)(p))

// ---------------------------------------------------------------------------
// Prepass: W fp32 (128 x 4096 row-major) -> bf16 MFMA B-fragments.
// Tile t in [0,256) covers cols t*16..t*16+16; fragment (t,kk) holds
// k = kk*32 + (lane>>4)*8 + j, n = t*16 + (lane&15), at wf[(t*4+kk)*512].
// ---------------------------------------------------------------------------
__global__ void wconv_kernel(const float* __restrict__ W, __bf16* __restrict__ wf) {
    int f    = blockIdx.x * 256 + threadIdx.x;  // 0..65535
    int lane = f & 63;
    int tkk  = f >> 6;
    int t    = tkk >> 2;
    int kk   = tkk & 3;
    int kbase = kk * 32 + (lane >> 4) * 8;
    int n     = t * 16 + (lane & 15);
    bf16x8 frag;
    for (int j = 0; j < 8; ++j)
        frag[j] = (__bf16)W[(kbase + j) * NCOL + n];
    *(bf16x8*)(wf + f * 8) = frag;
}

// ---------------------------------------------------------------------------
// Fused GEMM + bias + softmax(d) + p-contraction.
// Block: 256 thr (4 waves), 64 batch rows, one r-chunk w = blockIdx&3.
// Wave ww owns rows b0..b0+16.  Per c: the 8 tiles t=(c*8+d)*4+w are staged
// to LDS; 8 accumulators (one per d) live per lane; softmax over d is
// in-lane (8 exp2, 7-add tree, 1 rcp, 8 fma per jj).
// C/D layout: col=lane&15 (-> r), row=quad*4+jj (-> batch row).
// ---------------------------------------------------------------------------
__global__ __launch_bounds__(256, 4)
void fused_kernel(const float* __restrict__ x, const float* __restrict__ p,
                  const float* __restrict__ bias, const __bf16* __restrict__ wf,
                  float* __restrict__ out) {
    __shared__ __align__(16) char lds[32768];   // 32 fragments (8 d x 4 kk)

    const int lane = threadIdx.x & 63;
    const int ww   = threadIdx.x >> 6;   // wave 0..3 = m-tile
    const int quad = lane >> 4;
    const int l15  = lane & 15;
    const int w    = blockIdx.x & 3;     // r-chunk
    const int b0   = (blockIdx.x >> 2) * 64 + ww * 16;

    // A fragments: afr[kk][j] = x_bf16[b0+l15][kk*32 + quad*8 + j]
    bf16x8 afr[4];
    {
        const float* xr = x + (b0 + l15) * F_DIM + quad * 8;
#pragma unroll
        for (int kk = 0; kk < 4; ++kk) {
            float4 lo = *(const float4*)(xr + kk * 32);
            float4 hi = *(const float4*)(xr + kk * 32 + 4);
            bf16x8 f;
            f[0] = (__bf16)lo.x; f[1] = (__bf16)lo.y;
            f[2] = (__bf16)lo.z; f[3] = (__bf16)lo.w;
            f[4] = (__bf16)hi.x; f[5] = (__bf16)hi.y;
            f[6] = (__bf16)hi.z; f[7] = (__bf16)hi.w;
            afr[kk] = f;
        }
    }

    float O[8][4] = {};   // [d][jj] output accumulator over c

#pragma unroll 1
    for (int c = 0; c < 8; ++c) {
        // ---- stage c's 32 fragments: wave ww takes d = 2ww, 2ww+1 ---------
        {
#pragma unroll
            for (int j = 0; j < 8; ++j) {
                int d  = ww * 2 + (j >> 2);
                int kk = j & 3;
                int gf = ((c * 8 + d) * 4 + w) * 4 + kk;      // global frag
                __builtin_amdgcn_global_load_lds(
                    AS1(wf + (size_t)gf * 512 + lane * 8),
                    AS3(lds + (d * 4 + kk) * 1024), 16, 0, 0);
            }
        }
        __syncthreads();

        float pvv[4];
#pragma unroll
        for (int jj = 0; jj < 4; ++jj)
            pvv[jj] = p[(b0 + quad * 4 + jj) * 8 + c];

        float bvl[8];
#pragma unroll
        for (int d = 0; d < 8; ++d)
            bvl[d] = bias[(c * 8 + d) * 64 + w * 16 + l15] * LOG2E;

        f32x4 acc[8] = {};
#pragma unroll
        for (int kk = 0; kk < 4; ++kk)
#pragma unroll
            for (int d = 0; d < 8; ++d) {
                bf16x8 bfr = *(const bf16x8*)(lds + (d * 4 + kk) * 1024 + lane * 16);
                acc[d] = __builtin_amdgcn_mfma_f32_16x16x32_bf16(
                             afr[kk], bfr, acc[d], 0, 0, 0);
            }

#pragma unroll
        for (int jj = 0; jj < 4; ++jj) {
            float e[8];
#pragma unroll
            for (int d = 0; d < 8; ++d)
                e[d] = __builtin_amdgcn_exp2f(
                           __builtin_fmaf(acc[d][jj], LOG2E, bvl[d]));
            float s01 = e[0] + e[1], s23 = e[2] + e[3];
            float s45 = e[4] + e[5], s67 = e[6] + e[7];
            float s = (s01 + s23) + (s45 + s67);
            float scale = pvv[jj] * __builtin_amdgcn_rcpf(s);
#pragma unroll
            for (int d = 0; d < 8; ++d)
                O[d][jj] = __builtin_fmaf(e[d], scale, O[d][jj]);
        }
        __syncthreads();   // protect LDS before next c's staging
    }

    // ---- stores: out[b, d*64 + w*16 + l15] — coalesced 64B per quad -------
#pragma unroll
    for (int jj = 0; jj < 4; ++jj) {
        float* orow = out + (b0 + quad * 4 + jj) * OUT_STRIDE + w * 16 + l15;
#pragma unroll
        for (int d = 0; d < 8; ++d)
            orow[d * 64] = O[d][jj];
    }
}

extern "C" void kernel_launch(void* const* d_in, const int* in_sizes, int n_in,
                              void* d_out, int out_size, void* d_ws, size_t ws_size,
                              hipStream_t stream) {
    const float* x    = (const float*)d_in[0];   // (16384, 128)
    const float* p    = (const float*)d_in[1];   // (16384, 8)
    const float* W    = (const float*)d_in[2];   // (128, 64, 64)
    const float* bias = (const float*)d_in[3];   // (8, 8, 64)
    float* out = (float*)d_out;                  // (16384, 8, 64)
    __bf16* wf = (__bf16*)d_ws;                  // 1 MB bf16 fragments

    wconv_kernel<<<dim3(256), dim3(256), 0, stream>>>(W, wf);
    fused_kernel<<<dim3(1024), dim3(256), 0, stream>>>(x, p, bias, wf, out);
}